// Round 9
// baseline (411.236 us; speedup 1.0000x reference)
//
#include <hip/hip_runtime.h>
#include <hip/hip_bf16.h>

#define LEAKY 0.2f
#define LOG2E 1.44269504f

typedef __attribute__((ext_vector_type(8))) short short8;
typedef __attribute__((ext_vector_type(4))) float f32x4;

// round-to-nearest-even float -> bf16 bits (finite inputs)
__device__ inline unsigned short f2b(float f) {
    unsigned u = __float_as_uint(f);
    u += 0x7FFFu + ((u >> 16) & 1u);
    return (unsigned short)(u >> 16);
}
__device__ inline float b2f(unsigned short s) {
    return __uint_as_float(((unsigned)s) << 16);
}
// native 2^x (v_exp_f32)
__device__ inline float fexp2(float x) { return __builtin_amdgcn_exp2f(x); }

// async global->LDS, 16B per lane. LDS dest must be wave-uniform base
// (HW adds lane*16); global src is per-lane.
__device__ inline void gload16(const void* g, void* l) {
    __builtin_amdgcn_global_load_lds(
        (const __attribute__((address_space(1))) unsigned int*)g,
        (__attribute__((address_space(3))) unsigned int*)l,
        16, 0, 0);
}

#define NEB 8192   // edges per binning block

// ================= column permutation =================
// GEMM C-tiles are stored fragment-major: within each 64-col head block,
// true column c = cg*16+m16 is stored at s = m16*4+cg. Inverse:
// true(s) = 16*(s&3) + (s>>2). Wt2/Wt3 K-rows are permuted in k_prep;
// agg bias uses inverse-index loads; final fp32 output un-permutes.

// ---------------- fused prep + dst histogram ----------------

__global__ __launch_bounds__(256)
void k_prep(const float* __restrict__ features, unsigned short* __restrict__ fconv,
            int n4,
            const float* __restrict__ W1, const float* __restrict__ W2,
            const float* __restrict__ W3, unsigned short* __restrict__ Wt1,
            unsigned short* __restrict__ Wt2, unsigned short* __restrict__ Wt3,
            const int* __restrict__ dst, int* __restrict__ hist, int nbb,
            int E, int N) {
    __shared__ int lc[256];
    const int tid = threadIdx.x;
    if (blockIdx.x < nbb) {
        lc[tid] = 0;
        __syncthreads();
        const int b0 = blockIdx.x * NEB;
        const int cnt = min(NEB, E - b0);
        for (int j = 0; j < NEB / 256; ++j) {
            int idx = j * 256 + tid;
            if (idx < cnt) {
                int dn = dst[b0 + idx];
                if ((unsigned)dn < (unsigned)N) atomicAdd(&lc[dn >> 8], 1);
            }
        }
        __syncthreads();
        hist[blockIdx.x * 256 + tid] = lc[tid];
        return;
    }
    int idx = (blockIdx.x - nbb) * 256 + tid;
    if (idx < n4) {
        float4 v = *(const float4*)(features + idx * 4);
        ushort4 o;
        o.x = f2b(v.x); o.y = f2b(v.y); o.z = f2b(v.z); o.w = f2b(v.w);
        *(ushort4*)(fconv + idx * 4) = o;
        return;
    }
    int j = idx - n4;
    if (j < 32768) {                       // L1: K=128 (true order), M=256
        int m = j >> 7, k = j & 127;
        Wt1[j] = f2b(W1[(size_t)k * 256 + m]);
        return;
    }
    if (j < 98304) {                       // L2: K=256 stored-order, M=256
        int jj = j - 32768;
        int m = jj >> 8, ks = jj & 255;
        int kt = (ks & 192) | ((ks & 3) << 4) | ((ks & 63) >> 2);  // inverse perm
        Wt2[jj] = f2b(W2[(size_t)kt * 256 + m]);
        return;
    }
    if (j < 114688) {                      // L3: K=256 stored-order, M=64
        int jj = j - 98304;
        int m = jj >> 8, ks = jj & 255;
        int kt = (ks & 192) | ((ks & 3) << 4) | ((ks & 63) >> 2);
        Wt3[jj] = f2b(W3[(size_t)kt * 64 + m]);
    }
}

// ---------------- bucketed CSR build ----------------
// Each scatter block recomputes bucket bases from hist (coalesced, L2-hot)
// -> deterministic per-block destinations, no global atomics. ebuf entries
// pack (dst&255)<<24 | SRC VALUE (src < 2^24).

__global__ __launch_bounds__(256)
void k_bin_scatter(const int* __restrict__ dst, const int* __restrict__ src,
                   const int* __restrict__ hist, int nbb,
                   int* __restrict__ bbase, int* __restrict__ row_start,
                   int* __restrict__ ebuf, int E, int N, int B) {
    __shared__ int lc[256], lofs[256], lcur[256], gres[256];
    __shared__ int stage_v[NEB];
    __shared__ unsigned short stage_b[NEB];
    __shared__ int ws[4];
    const int tid = threadIdx.x, lane = tid & 63, wave = tid >> 6;
    const int b0 = blockIdx.x * NEB;
    const int cnt = min(NEB, E - b0);
    lc[tid] = 0;
    __syncthreads();

    int dreg[NEB / 256], sreg[NEB / 256];
    #pragma unroll
    for (int j = 0; j < NEB / 256; ++j) {
        int idx = j * 256 + tid;
        dreg[j] = -1;
        if (idx < cnt) {
            int dn = dst[b0 + idx];
            if ((unsigned)dn < (unsigned)N) {
                dreg[j] = dn;
                sreg[j] = src[b0 + idx];
                atomicAdd(&lc[dn >> 8], 1);
            }
        }
    }

    // global per-bucket base for this block: bbase[k] + sum_{b<blk} hist[b][k]
    int pre = 0, tot = 0;
    for (int b = 0; b < nbb; ++b) {
        int hv = hist[b * 256 + tid];
        tot += hv;
        if (b < (int)blockIdx.x) pre += hv;
    }
    {
        int x = tot;
        #pragma unroll
        for (int off = 1; off < 64; off <<= 1) {
            int t = __shfl_up(x, off, 64);
            if (lane >= off) x += t;
        }
        if (lane == 63) ws[wave] = x;
        __syncthreads();
        if (tid == 0) {
            int c = 0;
            #pragma unroll
            for (int wv = 0; wv < 4; ++wv) { int t = ws[wv]; ws[wv] = c; c += t; }
        }
        __syncthreads();
        int excl = x - tot + ws[wave];       // global bucket base
        gres[tid] = excl + pre;              // this block's slot in bucket tid
        if (blockIdx.x == 0) {
            bbase[tid] = excl;
            if (tid == 0) { bbase[256] = E; row_start[N] = E; }
        }
    }
    __syncthreads();
    // local per-bucket layout
    {
        int v = lc[tid];
        int x = v;
        #pragma unroll
        for (int off = 1; off < 64; off <<= 1) {
            int t = __shfl_up(x, off, 64);
            if (lane >= off) x += t;
        }
        if (lane == 63) ws[wave] = x;
        __syncthreads();
        if (tid == 0) {
            int c = 0;
            #pragma unroll
            for (int wv = 0; wv < 4; ++wv) { int t = ws[wv]; ws[wv] = c; c += t; }
        }
        __syncthreads();
        int excl = x - v + ws[wave];
        lofs[tid] = excl;
        lcur[tid] = excl;
    }
    __syncthreads();
    #pragma unroll
    for (int j = 0; j < NEB / 256; ++j) {
        int dn = dreg[j];
        if (dn >= 0) {
            int p = atomicAdd(&lcur[dn >> 8], 1);
            stage_v[p] = ((dn & 255) << 24) | sreg[j];
            stage_b[p] = (unsigned short)(dn >> 8);
        }
    }
    __syncthreads();
    int total = lcur[255];
    for (int i = tid; i < total; i += 256) {
        int k = stage_b[i];
        int destp = gres[k] + (i - lofs[k]);
        ebuf[destp] = stage_v[i];
    }
}

// per bucket: derive row_start, write src_sorted region, and emit a
// degree-DESCENDING node permutation (counting sort over 64 degree bins).
// agg waves host 2 (H=4) or 8 (H=1) nodes; wave time = max degree hosted.
// Poisson(16) degrees make that +15%/+40% over the mean. Sorting nodes by
// degree puts near-equal degrees in the same wave -> max ~= mean.
__global__ __launch_bounds__(256)
void k_csr_build(const int* __restrict__ ebuf,
                 const int* __restrict__ bbase, int* __restrict__ row_start,
                 int* __restrict__ src_sorted, int* __restrict__ perm, int N) {
    __shared__ int lc[256], lcur[256];
    __shared__ int ws[4];
    __shared__ int h2[64], c2[64];
    const int tid = threadIdx.x, lane = tid & 63, wave = tid >> 6;
    const int k = blockIdx.x;
    const int base = k << 8;
    const int e0 = bbase[k];
    const int cnt = bbase[k + 1] - e0;
    lc[tid] = 0;
    __syncthreads();
    for (int i = tid; i < cnt; i += 256) {
        int rel = ((unsigned)ebuf[e0 + i]) >> 24;
        atomicAdd(&lc[rel], 1);
    }
    __syncthreads();
    {
        int v = lc[tid];
        int x = v;
        #pragma unroll
        for (int off = 1; off < 64; off <<= 1) {
            int t = __shfl_up(x, off, 64);
            if (lane >= off) x += t;
        }
        if (lane == 63) ws[wave] = x;
        __syncthreads();
        if (tid == 0) {
            int c = 0;
            #pragma unroll
            for (int wv = 0; wv < 4; ++wv) { int t = ws[wv]; ws[wv] = c; c += t; }
        }
        __syncthreads();
        int excl = x - v + ws[wave];
        lcur[tid] = excl;
        int n = base + tid;
        if (n < N) row_start[n] = e0 + excl;
    }
    __syncthreads();
    for (int i = tid; i < cnt; i += 256) {
        int val = ebuf[e0 + i];
        int rel = ((unsigned)val) >> 24;
        int p = atomicAdd(&lcur[rel], 1);
        src_sorted[e0 + p] = val & 0xFFFFFF;
    }

    // ---- degree-descending counting sort -> perm ----
    __syncthreads();
    const bool valid = (base + tid < N);
    const int db = 63 - min(lc[tid], 63);   // key: descending degree
    if (tid < 64) h2[tid] = 0;
    __syncthreads();
    if (valid) atomicAdd(&h2[db], 1);
    __syncthreads();
    if (tid < 64) {
        int x = h2[tid];
        int ex = x;
        #pragma unroll
        for (int off = 1; off < 64; off <<= 1) {
            int t = __shfl_up(ex, off, 64);
            if (tid >= off) ex += t;
        }
        c2[tid] = ex - x;                   // exclusive prefix
    }
    __syncthreads();
    if (valid) {
        int p = atomicAdd(&c2[db], 1);
        perm[base + p] = base + tid;
    }
}

// ---------------- MFMA GEMM (BN=128), global_load_lds staging ----------------
// LDS tiles LINEAR [128 rows][32 ushorts]; both-sides XOR swizzle (rule #21):
// slot s of row r holds global chunk s^((r>>1)&3); read q' = q^((m16>>1)&3).
// el/er pre-scaled by LOG2E; C stored fragment-major (coalesced ushort4).

__global__ __launch_bounds__(256)
void k_gemm_mfma(const unsigned short* __restrict__ A, const unsigned short* __restrict__ Wt,
                 unsigned short* __restrict__ Cb, const float* __restrict__ al,
                 const float* __restrict__ ar, float* __restrict__ el,
                 float* __restrict__ er, int N, int K, int M) {
    __shared__ unsigned short As[128 * 32];
    __shared__ unsigned short Bs[128 * 32];
    const int tid  = threadIdx.x;
    const int wave = tid >> 6;
    const int lane = tid & 63;
    const int row0 = blockIdx.y * 128;
    const int col0 = blockIdx.x * 128;
    const int wr = (wave >> 1) * 64;
    const int wc = (wave & 1) * 64;
    const int m16 = lane & 15;
    const int q   = lane >> 4;

    const int c0   = wave * 2;
    const int rA   = c0 * 16 + (lane >> 2);
    const int sc   = (((lane & 3) ^ ((lane >> 3) & 3)) << 3);
    const int qsw  = (q ^ ((m16 >> 1) & 3)) * 8;

    f32x4 acc[4][4] = {};

    for (int k0 = 0; k0 < K; k0 += 32) {
        {
            int g1 = row0 + rA;      if (g1 > N - 1) g1 = N - 1;
            int g2 = row0 + rA + 16; if (g2 > N - 1) g2 = N - 1;
            gload16(A + (size_t)g1 * K + k0 + sc, &As[c0 * 512]);
            gload16(A + (size_t)g2 * K + k0 + sc, &As[c0 * 512 + 512]);
            gload16(Wt + (size_t)(col0 + rA) * K + k0 + sc, &Bs[c0 * 512]);
            gload16(Wt + (size_t)(col0 + rA + 16) * K + k0 + sc, &Bs[c0 * 512 + 512]);
        }
        __syncthreads();

        short8 afr[4], bfr[4];
        #pragma unroll
        for (int rg = 0; rg < 4; ++rg)
            afr[rg] = *(const short8*)&As[(wr + rg * 16 + m16) * 32 + qsw];
        #pragma unroll
        for (int cg = 0; cg < 4; ++cg)
            bfr[cg] = *(const short8*)&Bs[(wc + cg * 16 + m16) * 32 + qsw];
        #pragma unroll
        for (int rg = 0; rg < 4; ++rg)
            #pragma unroll
            for (int cg = 0; cg < 4; ++cg)
                acc[rg][cg] = __builtin_amdgcn_mfma_f32_16x16x32_bf16(
                    afr[rg], bfr[cg], acc[rg][cg], 0, 0, 0);
        __syncthreads();
    }

    const int H = M >> 6;
    const int h = (col0 + wc) >> 6;
    float alv[4], arv[4];
    #pragma unroll
    for (int cg = 0; cg < 4; ++cg) {
        alv[cg] = al[h * 64 + cg * 16 + m16];
        arv[cg] = ar[h * 64 + cg * 16 + m16];
    }

    #pragma unroll
    for (int rg = 0; rg < 4; ++rg) {
        #pragma unroll
        for (int r = 0; r < 4; ++r) {
            int gr = row0 + wr + rg * 16 + q * 4 + r;
            float pl = 0.f, pr = 0.f;
            #pragma unroll
            for (int cg = 0; cg < 4; ++cg) {
                pl = fmaf(acc[rg][cg][r], alv[cg], pl);
                pr = fmaf(acc[rg][cg][r], arv[cg], pr);
            }
            #pragma unroll
            for (int off = 1; off < 16; off <<= 1) {
                pl += __shfl_xor(pl, off, 64);
                pr += __shfl_xor(pr, off, 64);
            }
            if (gr < N) {
                ushort4 o;
                o.x = f2b(acc[rg][0][r]); o.y = f2b(acc[rg][1][r]);
                o.z = f2b(acc[rg][2][r]); o.w = f2b(acc[rg][3][r]);
                *(ushort4*)(Cb + (size_t)gr * M + (col0 + wc) + m16 * 4) = o;
                if (m16 == 0) {
                    el[gr * H + h] = pl * LOG2E;
                    er[gr * H + h] = pr * LOG2E;
                }
            }
        }
    }
}

// ---------------- MFMA GEMM (M=64): 256x64 tile + fused el/er (H=1) ----------

__global__ __launch_bounds__(256)
void k_gemm_mfma64(const unsigned short* __restrict__ A, const unsigned short* __restrict__ Wt,
                   unsigned short* __restrict__ Cb, const float* __restrict__ al,
                   const float* __restrict__ ar, float* __restrict__ el,
                   float* __restrict__ er, int N, int K) {
    constexpr int M = 64;
    constexpr int STR = 40;
    __shared__ unsigned short As[256 * STR];
    __shared__ unsigned short Bs[64 * STR];
    const int tid  = threadIdx.x;
    const int wave = tid >> 6;
    const int lane = tid & 63;
    const int row0 = blockIdx.x * 256;
    const int wr = wave * 64;
    const int m16 = lane & 15;
    const int q   = lane >> 4;

    const int s_row = tid >> 1;
    const int s_off = (tid & 1) * 16;
    const int b_row = tid >> 2;
    const int b_chk = (tid & 3) * 8;

    f32x4 acc[4][4] = {};

    for (int k0 = 0; k0 < K; k0 += 32) {
        #pragma unroll
        for (int p = 0; p < 2; ++p) {
            int r = s_row + p * 128;
            int gr = row0 + r;
            short8 z = {};
            short8 v0 = z, v1 = z;
            if (gr < N) {
                const unsigned short* ap = A + (size_t)gr * K + k0 + s_off;
                v0 = *(const short8*)ap;
                v1 = *(const short8*)(ap + 8);
            }
            *(short8*)&As[r * STR + s_off]     = v0;
            *(short8*)&As[r * STR + s_off + 8] = v1;
        }
        {
            const unsigned short* sp = Wt + (size_t)b_row * K + k0 + b_chk;
            *(short8*)&Bs[b_row * STR + b_chk] = *(const short8*)sp;
        }
        __syncthreads();

        short8 afr[4], bfr[4];
        #pragma unroll
        for (int rg = 0; rg < 4; ++rg)
            afr[rg] = *(const short8*)&As[(wr + rg * 16 + m16) * STR + q * 8];
        #pragma unroll
        for (int cg = 0; cg < 4; ++cg)
            bfr[cg] = *(const short8*)&Bs[(cg * 16 + m16) * STR + q * 8];
        #pragma unroll
        for (int rg = 0; rg < 4; ++rg)
            #pragma unroll
            for (int cg = 0; cg < 4; ++cg)
                acc[rg][cg] = __builtin_amdgcn_mfma_f32_16x16x32_bf16(
                    afr[rg], bfr[cg], acc[rg][cg], 0, 0, 0);
        __syncthreads();
    }

    float alv[4], arv[4];
    #pragma unroll
    for (int cg = 0; cg < 4; ++cg) {
        alv[cg] = al[cg * 16 + m16];
        arv[cg] = ar[cg * 16 + m16];
    }

    #pragma unroll
    for (int rg = 0; rg < 4; ++rg) {
        #pragma unroll
        for (int r = 0; r < 4; ++r) {
            int gr = row0 + wr + rg * 16 + q * 4 + r;
            float pl = 0.f, pr = 0.f;
            #pragma unroll
            for (int cg = 0; cg < 4; ++cg) {
                pl = fmaf(acc[rg][cg][r], alv[cg], pl);
                pr = fmaf(acc[rg][cg][r], arv[cg], pr);
            }
            #pragma unroll
            for (int off = 1; off < 16; off <<= 1) {
                pl += __shfl_xor(pl, off, 64);
                pr += __shfl_xor(pr, off, 64);
            }
            if (gr < N) {
                ushort4 o;
                o.x = f2b(acc[rg][0][r]); o.y = f2b(acc[rg][1][r]);
                o.z = f2b(acc[rg][2][r]); o.w = f2b(acc[rg][3][r]);
                *(ushort4*)(Cb + (size_t)gr * M + m16 * 4) = o;
                if (m16 == 0) {
                    el[gr] = pl * LOG2E;
                    er[gr] = pr * LOG2E;
                }
            }
        }
    }
}

// ---------------- fused softmax + aggregation (degree-sorted groups) ----------
// n = perm[position]: nodes ordered by descending degree within each bucket,
// so each wave hosts near-equal-degree nodes (wave time = max degree hosted).
template<int OUTBF, int HH>
__global__ __launch_bounds__(256)
void k_agg_f(const int* __restrict__ row_start, const int* __restrict__ src_sorted,
             const uint4* __restrict__ featp, const float* __restrict__ el,
             const float* __restrict__ er, const float* __restrict__ bias,
             const int* __restrict__ perm,
             void* __restrict__ outv, int N, int do_relu) {
    constexpr int M = HH * 64;
    constexpr int P = M >> 3;
    constexpr int G = 256 / P;
    const int grp = threadIdx.x / P;
    const int t = threadIdx.x - grp * P;
    const int pos = blockIdx.x * G + grp;
    if (pos >= N) return;
    const int n = perm[pos];
    const int d0 = t * 8;          // stored-dim base
    const int h = d0 >> 6;
    const float erv = er[n * HH + h];

    const int b0 = row_start[n], b1 = row_start[n + 1];

    float a[8] = {};
    float sum = 0.f;
    int i = b0;

    int ssP[8];
    if (i + 8 <= b1) {
        #pragma unroll
        for (int j = 0; j < 8; ++j) ssP[j] = src_sorted[i + j];
    }
    for (; i + 8 <= b1; i += 8) {
        int ss[8];
        #pragma unroll
        for (int j = 0; j < 8; ++j) ss[j] = ssP[j];
        if (i + 16 <= b1) {
            #pragma unroll
            for (int j = 0; j < 8; ++j) ssP[j] = src_sorted[i + 8 + j];
        }
        float wv[8]; uint4 pv[8];
        #pragma unroll
        for (int j = 0; j < 8; ++j) wv[j] = el[(unsigned)(ss[j] * HH + h)];
        #pragma unroll
        for (int j = 0; j < 8; ++j) pv[j] = featp[(unsigned)(ss[j] * P + t)];
        #pragma unroll
        for (int j = 0; j < 8; ++j) {
            float x = wv[j] + erv;
            x = fmaxf(x, LEAKY * x);
            float w = fexp2(x);
            wv[j] = w;
            sum += w;
        }
        #pragma unroll
        for (int j = 0; j < 8; ++j) {
            a[0] = fmaf(__uint_as_float(pv[j].x << 16),         wv[j], a[0]);
            a[1] = fmaf(__uint_as_float(pv[j].x & 0xFFFF0000u), wv[j], a[1]);
            a[2] = fmaf(__uint_as_float(pv[j].y << 16),         wv[j], a[2]);
            a[3] = fmaf(__uint_as_float(pv[j].y & 0xFFFF0000u), wv[j], a[3]);
            a[4] = fmaf(__uint_as_float(pv[j].z << 16),         wv[j], a[4]);
            a[5] = fmaf(__uint_as_float(pv[j].z & 0xFFFF0000u), wv[j], a[5]);
            a[6] = fmaf(__uint_as_float(pv[j].w << 16),         wv[j], a[6]);
            a[7] = fmaf(__uint_as_float(pv[j].w & 0xFFFF0000u), wv[j], a[7]);
        }
    }
    for (; i + 4 <= b1; i += 4) {
        int ss[4]; float wv[4]; uint4 pv[4];
        #pragma unroll
        for (int j = 0; j < 4; ++j) ss[j] = src_sorted[i + j];
        #pragma unroll
        for (int j = 0; j < 4; ++j) wv[j] = el[(unsigned)(ss[j] * HH + h)];
        #pragma unroll
        for (int j = 0; j < 4; ++j) pv[j] = featp[(unsigned)(ss[j] * P + t)];
        #pragma unroll
        for (int j = 0; j < 4; ++j) {
            float x = wv[j] + erv;
            x = fmaxf(x, LEAKY * x);
            float w = fexp2(x);
            wv[j] = w;
            sum += w;
        }
        #pragma unroll
        for (int j = 0; j < 4; ++j) {
            a[0] = fmaf(__uint_as_float(pv[j].x << 16),         wv[j], a[0]);
            a[1] = fmaf(__uint_as_float(pv[j].x & 0xFFFF0000u), wv[j], a[1]);
            a[2] = fmaf(__uint_as_float(pv[j].y << 16),         wv[j], a[2]);
            a[3] = fmaf(__uint_as_float(pv[j].y & 0xFFFF0000u), wv[j], a[3]);
            a[4] = fmaf(__uint_as_float(pv[j].z << 16),         wv[j], a[4]);
            a[5] = fmaf(__uint_as_float(pv[j].z & 0xFFFF0000u), wv[j], a[5]);
            a[6] = fmaf(__uint_as_float(pv[j].w << 16),         wv[j], a[6]);
            a[7] = fmaf(__uint_as_float(pv[j].w & 0xFFFF0000u), wv[j], a[7]);
        }
    }
    for (; i < b1; ++i) {
        int ss = src_sorted[i];
        float x = el[(unsigned)(ss * HH + h)] + erv;
        uint4 pv = featp[(unsigned)(ss * P + t)];
        x = fmaxf(x, LEAKY * x);
        float w = fexp2(x);
        sum += w;
        a[0] = fmaf(__uint_as_float(pv.x << 16),         w, a[0]);
        a[1] = fmaf(__uint_as_float(pv.x & 0xFFFF0000u), w, a[1]);
        a[2] = fmaf(__uint_as_float(pv.y << 16),         w, a[2]);
        a[3] = fmaf(__uint_as_float(pv.y & 0xFFFF0000u), w, a[3]);
        a[4] = fmaf(__uint_as_float(pv.z << 16),         w, a[4]);
        a[5] = fmaf(__uint_as_float(pv.z & 0xFFFF0000u), w, a[5]);
        a[6] = fmaf(__uint_as_float(pv.w << 16),         w, a[6]);
        a[7] = fmaf(__uint_as_float(pv.w & 0xFFFF0000u), w, a[7]);
    }

    float rs = 1.0f / fmaxf(sum, 1e-30f);
    // bias for stored dim d0+j: true pos = 16*(j&3) + c0 + (j>>2), c0 = (d0&63)>>2
    const int c0 = (d0 & 63) >> 2;
    const float* bh = bias + h * 64 + c0;
    #pragma unroll
    for (int j = 0; j < 8; ++j)
        a[j] = fmaf(a[j], rs, bh[16 * (j & 3) + (j >> 2)]);
    if (do_relu) {
        #pragma unroll
        for (int j = 0; j < 8; ++j) a[j] = fmaxf(a[j], 0.f);
    }
    if (OUTBF) {
        uint4 o;
        o.x = (unsigned)f2b(a[0]) | ((unsigned)f2b(a[1]) << 16);
        o.y = (unsigned)f2b(a[2]) | ((unsigned)f2b(a[3]) << 16);
        o.z = (unsigned)f2b(a[4]) | ((unsigned)f2b(a[5]) << 16);
        o.w = (unsigned)f2b(a[6]) | ((unsigned)f2b(a[7]) << 16);
        *(uint4*)((unsigned short*)outv + (size_t)n * M + d0) = o;
    } else {
        float* op = (float*)outv + (size_t)n * M + h * 64 + c0;
        #pragma unroll
        for (int j = 0; j < 4; ++j)
            *(float2*)(op + 16 * j) = make_float2(a[j], a[j + 4]);
    }
}

// ---------------- host side ----------------

static void run_layer(const unsigned short* A, int K, const unsigned short* Wt,
                      const float* al_, const float* ar_, const float* b_, int H,
                      unsigned short* featb, void* rstOut, bool outBf,
                      float* el, float* er,
                      const int* row_start, const int* src_sorted, const int* perm,
                      int N, int E, bool do_relu, hipStream_t stream) {
    const int M = H * 64;
    if (M % 128 == 0) {
        dim3 gg(M / 128, (N + 127) / 128);
        k_gemm_mfma<<<gg, 256, 0, stream>>>(A, Wt, featb, al_, ar_, el, er, N, K, M);
    } else {
        k_gemm_mfma64<<<(N + 255) / 256, 256, 0, stream>>>(A, Wt, featb, al_, ar_, el, er, N, K);
    }

    int G = 256 / (M / 8);
    int blocks = (N + G - 1) / G;
    if (H == 4) {
        if (outBf)
            k_agg_f<1, 4><<<blocks, 256, 0, stream>>>(row_start, src_sorted,
                                                      (const uint4*)featb, el, er,
                                                      b_, perm, rstOut, N, do_relu ? 1 : 0);
        else
            k_agg_f<0, 4><<<blocks, 256, 0, stream>>>(row_start, src_sorted,
                                                      (const uint4*)featb, el, er,
                                                      b_, perm, rstOut, N, do_relu ? 1 : 0);
    } else {
        if (outBf)
            k_agg_f<1, 1><<<blocks, 256, 0, stream>>>(row_start, src_sorted,
                                                      (const uint4*)featb, el, er,
                                                      b_, perm, rstOut, N, do_relu ? 1 : 0);
        else
            k_agg_f<0, 1><<<blocks, 256, 0, stream>>>(row_start, src_sorted,
                                                      (const uint4*)featb, el, er,
                                                      b_, perm, rstOut, N, do_relu ? 1 : 0);
    }
}

extern "C" void kernel_launch(void* const* d_in, const int* in_sizes, int n_in,
                              void* d_out, int out_size, void* d_ws, size_t ws_size,
                              hipStream_t stream) {
    const float* features = (const float*)d_in[0];
    const int*   src = (const int*)d_in[1];
    const int*   dst = (const int*)d_in[2];
    const float* W1  = (const float*)d_in[3];
    const float* al1 = (const float*)d_in[4];
    const float* ar1 = (const float*)d_in[5];
    const float* b1  = (const float*)d_in[6];
    const float* W2  = (const float*)d_in[7];
    const float* al2 = (const float*)d_in[8];
    const float* ar2 = (const float*)d_in[9];
    const float* b2  = (const float*)d_in[10];
    const float* W3  = (const float*)d_in[11];
    const float* al3 = (const float*)d_in[12];
    const float* ar3 = (const float*)d_in[13];
    const float* b3  = (const float*)d_in[14];

    const int N = in_sizes[0] / 128;   // 50000
    const int E = in_sizes[1];         // 800000
    const int B = (N + 255) >> 8;      // buckets (196)
    const int n4 = N * 128 / 4;        // convert chunks
    const int nbb = (E + NEB - 1) / NEB;   // binning blocks (98)

    float* ws   = (float*)d_ws;
    float* el   = ws;                        // [N,4]
    float* er   = el + (size_t)N * 4;        // [N,4]
    int* row_start  = (int*)(er + (size_t)N * 4);  // [N+1]
    int* src_sorted = row_start + N + 1;            // [E]
    int* ebuf       = src_sorted + E;               // [E]
    int* bbase      = ebuf + E;                     // [257]
    int* perm       = bbase + 257;                  // [N]
    int* hist       = perm + N;                     // [nbb*256]
    uintptr_t wp = (uintptr_t)(hist + (size_t)nbb * 256);
    wp = (wp + 15) & ~(uintptr_t)15;
    unsigned short* Wt1   = (unsigned short*)wp;       // [256*128]
    unsigned short* Wt2   = Wt1 + 32768;               // [256*256] K-permuted
    unsigned short* Wt3   = Wt2 + 65536;               // [64*256]  K-permuted
    unsigned short* fconv = Wt3 + 16384;               // [N,128] bf16 features
    unsigned short* featb = fconv + (size_t)N * 128;   // [N,256] GEMM out (stored order)
    unsigned short* rstb  = featb + (size_t)N * 256;   // [N,256] agg out (stored order)

    // ---- fused prep: dst histogram + convert + weight transpose ----
    int prep_total = n4 + 114688;
    int prep_blocks = nbb + (prep_total + 255) / 256;
    k_prep<<<prep_blocks, 256, 0, stream>>>(features, fconv, n4,
                                            W1, W2, W3, Wt1, Wt2, Wt3,
                                            dst, hist, nbb, E, N);

    // ---- bucketed CSR build (deterministic offsets, src packed into ebuf) ----
    k_bin_scatter<<<nbb, 256, 0, stream>>>(dst, src, hist, nbb, bbase,
                                           row_start, ebuf, E, N, B);
    k_csr_build<<<B, 256, 0, stream>>>(ebuf, bbase, row_start, src_sorted, perm, N);

    // layer 1: A=fconv[N,128] -> featb[N,256] (+el/er fused) -> rstb bf16 (+relu)
    run_layer(fconv, 128, Wt1, al1, ar1, b1, 4, featb, rstb, true,
              el, er, row_start, src_sorted, perm, N, E, true, stream);
    // layer 2
    run_layer(rstb, 256, Wt2, al2, ar2, b2, 4, featb, rstb, true,
              el, er, row_start, src_sorted, perm, N, E, true, stream);
    // layer 3: H=1 -> d_out fp32 (mean over 1 head = id), un-permuted write
    run_layer(rstb, 256, Wt3, al3, ar3, b3, 1, featb, d_out, false,
              el, er, row_start, src_sorted, perm, N, E, false, stream);
}

// Round 10
// 384.278 us; speedup vs baseline: 1.0702x; 1.0702x over previous
//
#include <hip/hip_runtime.h>
#include <hip/hip_bf16.h>

#define LEAKY 0.2f
#define LOG2E 1.44269504f

typedef __attribute__((ext_vector_type(8))) short short8;
typedef __attribute__((ext_vector_type(4))) float f32x4;

// round-to-nearest-even float -> bf16 bits (finite inputs)
__device__ inline unsigned short f2b(float f) {
    unsigned u = __float_as_uint(f);
    u += 0x7FFFu + ((u >> 16) & 1u);
    return (unsigned short)(u >> 16);
}
__device__ inline float b2f(unsigned short s) {
    return __uint_as_float(((unsigned)s) << 16);
}
// native 2^x (v_exp_f32)
__device__ inline float fexp2(float x) { return __builtin_amdgcn_exp2f(x); }

// async global->LDS, 16B per lane. LDS dest must be wave-uniform base
// (HW adds lane*16); global src is per-lane.
__device__ inline void gload16(const void* g, void* l) {
    __builtin_amdgcn_global_load_lds(
        (const __attribute__((address_space(1))) unsigned int*)g,
        (__attribute__((address_space(3))) unsigned int*)l,
        16, 0, 0);
}

#define NEB 8192   // edges per binning block

// ================= column permutation =================
// GEMM C-tiles are stored fragment-major: within each 64-col head block,
// true column c = cg*16+m16 is stored at s = m16*4+cg. Inverse:
// true(s) = 16*(s&3) + (s>>2). Wt2/Wt3 K-rows are permuted in k_prep;
// agg bias uses inverse-index loads; final fp32 output un-permutes.

// ---------------- fused prep + dst histogram ----------------

__global__ __launch_bounds__(256)
void k_prep(const float* __restrict__ features, unsigned short* __restrict__ fconv,
            int n4,
            const float* __restrict__ W1, const float* __restrict__ W2,
            const float* __restrict__ W3, unsigned short* __restrict__ Wt1,
            unsigned short* __restrict__ Wt2, unsigned short* __restrict__ Wt3,
            const int* __restrict__ dst, int* __restrict__ hist, int nbb,
            int E, int N) {
    __shared__ int lc[256];
    const int tid = threadIdx.x;
    if (blockIdx.x < nbb) {
        lc[tid] = 0;
        __syncthreads();
        const int b0 = blockIdx.x * NEB;
        const int cnt = min(NEB, E - b0);
        for (int j = 0; j < NEB / 256; ++j) {
            int idx = j * 256 + tid;
            if (idx < cnt) {
                int dn = dst[b0 + idx];
                if ((unsigned)dn < (unsigned)N) atomicAdd(&lc[dn >> 8], 1);
            }
        }
        __syncthreads();
        hist[blockIdx.x * 256 + tid] = lc[tid];
        return;
    }
    int idx = (blockIdx.x - nbb) * 256 + tid;
    if (idx < n4) {
        float4 v = *(const float4*)(features + idx * 4);
        ushort4 o;
        o.x = f2b(v.x); o.y = f2b(v.y); o.z = f2b(v.z); o.w = f2b(v.w);
        *(ushort4*)(fconv + idx * 4) = o;
        return;
    }
    int j = idx - n4;
    if (j < 32768) {                       // L1: K=128 (true order), M=256
        int m = j >> 7, k = j & 127;
        Wt1[j] = f2b(W1[(size_t)k * 256 + m]);
        return;
    }
    if (j < 98304) {                       // L2: K=256 stored-order, M=256
        int jj = j - 32768;
        int m = jj >> 8, ks = jj & 255;
        int kt = (ks & 192) | ((ks & 3) << 4) | ((ks & 63) >> 2);  // inverse perm
        Wt2[jj] = f2b(W2[(size_t)kt * 256 + m]);
        return;
    }
    if (j < 114688) {                      // L3: K=256 stored-order, M=64
        int jj = j - 98304;
        int m = jj >> 8, ks = jj & 255;
        int kt = (ks & 192) | ((ks & 3) << 4) | ((ks & 63) >> 2);
        Wt3[jj] = f2b(W3[(size_t)kt * 64 + m]);
    }
}

// ---------------- bucketed CSR build ----------------
// Each scatter block recomputes bucket bases from hist (coalesced, L2-hot)
// -> deterministic per-block destinations, no global atomics. ebuf entries
// pack (dst&255)<<24 | SRC VALUE (src < 2^24).

__global__ __launch_bounds__(256)
void k_bin_scatter(const int* __restrict__ dst, const int* __restrict__ src,
                   const int* __restrict__ hist, int nbb,
                   int* __restrict__ bbase, int* __restrict__ row_start,
                   int* __restrict__ ebuf, int E, int N, int B) {
    __shared__ int lc[256], lofs[256], lcur[256], gres[256];
    __shared__ int stage_v[NEB];
    __shared__ unsigned short stage_b[NEB];
    __shared__ int ws[4];
    const int tid = threadIdx.x, lane = tid & 63, wave = tid >> 6;
    const int b0 = blockIdx.x * NEB;
    const int cnt = min(NEB, E - b0);
    lc[tid] = 0;
    __syncthreads();

    int dreg[NEB / 256], sreg[NEB / 256];
    #pragma unroll
    for (int j = 0; j < NEB / 256; ++j) {
        int idx = j * 256 + tid;
        dreg[j] = -1;
        if (idx < cnt) {
            int dn = dst[b0 + idx];
            if ((unsigned)dn < (unsigned)N) {
                dreg[j] = dn;
                sreg[j] = src[b0 + idx];
                atomicAdd(&lc[dn >> 8], 1);
            }
        }
    }

    // global per-bucket base for this block: bbase[k] + sum_{b<blk} hist[b][k]
    int pre = 0, tot = 0;
    for (int b = 0; b < nbb; ++b) {
        int hv = hist[b * 256 + tid];
        tot += hv;
        if (b < (int)blockIdx.x) pre += hv;
    }
    {
        int x = tot;
        #pragma unroll
        for (int off = 1; off < 64; off <<= 1) {
            int t = __shfl_up(x, off, 64);
            if (lane >= off) x += t;
        }
        if (lane == 63) ws[wave] = x;
        __syncthreads();
        if (tid == 0) {
            int c = 0;
            #pragma unroll
            for (int wv = 0; wv < 4; ++wv) { int t = ws[wv]; ws[wv] = c; c += t; }
        }
        __syncthreads();
        int excl = x - tot + ws[wave];       // global bucket base
        gres[tid] = excl + pre;              // this block's slot in bucket tid
        if (blockIdx.x == 0) {
            bbase[tid] = excl;
            if (tid == 0) { bbase[256] = E; row_start[N] = E; }
        }
    }
    __syncthreads();
    // local per-bucket layout
    {
        int v = lc[tid];
        int x = v;
        #pragma unroll
        for (int off = 1; off < 64; off <<= 1) {
            int t = __shfl_up(x, off, 64);
            if (lane >= off) x += t;
        }
        if (lane == 63) ws[wave] = x;
        __syncthreads();
        if (tid == 0) {
            int c = 0;
            #pragma unroll
            for (int wv = 0; wv < 4; ++wv) { int t = ws[wv]; ws[wv] = c; c += t; }
        }
        __syncthreads();
        int excl = x - v + ws[wave];
        lofs[tid] = excl;
        lcur[tid] = excl;
    }
    __syncthreads();
    #pragma unroll
    for (int j = 0; j < NEB / 256; ++j) {
        int dn = dreg[j];
        if (dn >= 0) {
            int p = atomicAdd(&lcur[dn >> 8], 1);
            stage_v[p] = ((dn & 255) << 24) | sreg[j];
            stage_b[p] = (unsigned short)(dn >> 8);
        }
    }
    __syncthreads();
    int total = lcur[255];
    for (int i = tid; i < total; i += 256) {
        int k = stage_b[i];
        int destp = gres[k] + (i - lofs[k]);
        ebuf[destp] = stage_v[i];
    }
}

// per bucket: derive row_start for its 256 nodes and write src_sorted region.
__global__ __launch_bounds__(256)
void k_csr_build(const int* __restrict__ ebuf,
                 const int* __restrict__ bbase, int* __restrict__ row_start,
                 int* __restrict__ src_sorted, int N) {
    __shared__ int lc[256], lcur[256];
    __shared__ int ws[4];
    const int tid = threadIdx.x, lane = tid & 63, wave = tid >> 6;
    const int k = blockIdx.x;
    const int base = k << 8;
    const int e0 = bbase[k];
    const int cnt = bbase[k + 1] - e0;
    lc[tid] = 0;
    __syncthreads();
    for (int i = tid; i < cnt; i += 256) {
        int rel = ((unsigned)ebuf[e0 + i]) >> 24;
        atomicAdd(&lc[rel], 1);
    }
    __syncthreads();
    {
        int v = lc[tid];
        int x = v;
        #pragma unroll
        for (int off = 1; off < 64; off <<= 1) {
            int t = __shfl_up(x, off, 64);
            if (lane >= off) x += t;
        }
        if (lane == 63) ws[wave] = x;
        __syncthreads();
        if (tid == 0) {
            int c = 0;
            #pragma unroll
            for (int wv = 0; wv < 4; ++wv) { int t = ws[wv]; ws[wv] = c; c += t; }
        }
        __syncthreads();
        int excl = x - v + ws[wave];
        lcur[tid] = excl;
        int n = base + tid;
        if (n < N) row_start[n] = e0 + excl;
    }
    __syncthreads();
    for (int i = tid; i < cnt; i += 256) {
        int val = ebuf[e0 + i];
        int rel = ((unsigned)val) >> 24;
        int p = atomicAdd(&lcur[rel], 1);
        src_sorted[e0 + p] = val & 0xFFFFFF;
    }
}

// ---------------- MFMA GEMM (BN=128), global_load_lds staging ----------------
// LDS tiles LINEAR [128 rows][32 ushorts]; both-sides XOR swizzle (rule #21):
// slot s of row r holds global chunk s^((r>>1)&3); read q' = q^((m16>>1)&3).
// el/er pre-scaled by LOG2E; C stored fragment-major (coalesced ushort4).

__global__ __launch_bounds__(256)
void k_gemm_mfma(const unsigned short* __restrict__ A, const unsigned short* __restrict__ Wt,
                 unsigned short* __restrict__ Cb, const float* __restrict__ al,
                 const float* __restrict__ ar, float* __restrict__ el,
                 float* __restrict__ er, int N, int K, int M) {
    __shared__ unsigned short As[128 * 32];
    __shared__ unsigned short Bs[128 * 32];
    const int tid  = threadIdx.x;
    const int wave = tid >> 6;
    const int lane = tid & 63;
    const int row0 = blockIdx.y * 128;
    const int col0 = blockIdx.x * 128;
    const int wr = (wave >> 1) * 64;
    const int wc = (wave & 1) * 64;
    const int m16 = lane & 15;
    const int q   = lane >> 4;

    const int c0   = wave * 2;
    const int rA   = c0 * 16 + (lane >> 2);
    const int sc   = (((lane & 3) ^ ((lane >> 3) & 3)) << 3);
    const int qsw  = (q ^ ((m16 >> 1) & 3)) * 8;

    f32x4 acc[4][4] = {};

    for (int k0 = 0; k0 < K; k0 += 32) {
        {
            int g1 = row0 + rA;      if (g1 > N - 1) g1 = N - 1;
            int g2 = row0 + rA + 16; if (g2 > N - 1) g2 = N - 1;
            gload16(A + (size_t)g1 * K + k0 + sc, &As[c0 * 512]);
            gload16(A + (size_t)g2 * K + k0 + sc, &As[c0 * 512 + 512]);
            gload16(Wt + (size_t)(col0 + rA) * K + k0 + sc, &Bs[c0 * 512]);
            gload16(Wt + (size_t)(col0 + rA + 16) * K + k0 + sc, &Bs[c0 * 512 + 512]);
        }
        __syncthreads();

        short8 afr[4], bfr[4];
        #pragma unroll
        for (int rg = 0; rg < 4; ++rg)
            afr[rg] = *(const short8*)&As[(wr + rg * 16 + m16) * 32 + qsw];
        #pragma unroll
        for (int cg = 0; cg < 4; ++cg)
            bfr[cg] = *(const short8*)&Bs[(wc + cg * 16 + m16) * 32 + qsw];
        #pragma unroll
        for (int rg = 0; rg < 4; ++rg)
            #pragma unroll
            for (int cg = 0; cg < 4; ++cg)
                acc[rg][cg] = __builtin_amdgcn_mfma_f32_16x16x32_bf16(
                    afr[rg], bfr[cg], acc[rg][cg], 0, 0, 0);
        __syncthreads();
    }

    const int H = M >> 6;
    const int h = (col0 + wc) >> 6;
    float alv[4], arv[4];
    #pragma unroll
    for (int cg = 0; cg < 4; ++cg) {
        alv[cg] = al[h * 64 + cg * 16 + m16];
        arv[cg] = ar[h * 64 + cg * 16 + m16];
    }

    #pragma unroll
    for (int rg = 0; rg < 4; ++rg) {
        #pragma unroll
        for (int r = 0; r < 4; ++r) {
            int gr = row0 + wr + rg * 16 + q * 4 + r;
            float pl = 0.f, pr = 0.f;
            #pragma unroll
            for (int cg = 0; cg < 4; ++cg) {
                pl = fmaf(acc[rg][cg][r], alv[cg], pl);
                pr = fmaf(acc[rg][cg][r], arv[cg], pr);
            }
            #pragma unroll
            for (int off = 1; off < 16; off <<= 1) {
                pl += __shfl_xor(pl, off, 64);
                pr += __shfl_xor(pr, off, 64);
            }
            if (gr < N) {
                ushort4 o;
                o.x = f2b(acc[rg][0][r]); o.y = f2b(acc[rg][1][r]);
                o.z = f2b(acc[rg][2][r]); o.w = f2b(acc[rg][3][r]);
                *(ushort4*)(Cb + (size_t)gr * M + (col0 + wc) + m16 * 4) = o;
                if (m16 == 0) {
                    el[gr * H + h] = pl * LOG2E;
                    er[gr * H + h] = pr * LOG2E;
                }
            }
        }
    }
}

// ---------------- MFMA GEMM (M=64): 256x64 tile + fused el/er (H=1) ----------

__global__ __launch_bounds__(256)
void k_gemm_mfma64(const unsigned short* __restrict__ A, const unsigned short* __restrict__ Wt,
                   unsigned short* __restrict__ Cb, const float* __restrict__ al,
                   const float* __restrict__ ar, float* __restrict__ el,
                   float* __restrict__ er, int N, int K) {
    constexpr int M = 64;
    constexpr int STR = 40;
    __shared__ unsigned short As[256 * STR];
    __shared__ unsigned short Bs[64 * STR];
    const int tid  = threadIdx.x;
    const int wave = tid >> 6;
    const int lane = tid & 63;
    const int row0 = blockIdx.x * 256;
    const int wr = wave * 64;
    const int m16 = lane & 15;
    const int q   = lane >> 4;

    const int s_row = tid >> 1;
    const int s_off = (tid & 1) * 16;
    const int b_row = tid >> 2;
    const int b_chk = (tid & 3) * 8;

    f32x4 acc[4][4] = {};

    for (int k0 = 0; k0 < K; k0 += 32) {
        #pragma unroll
        for (int p = 0; p < 2; ++p) {
            int r = s_row + p * 128;
            int gr = row0 + r;
            short8 z = {};
            short8 v0 = z, v1 = z;
            if (gr < N) {
                const unsigned short* ap = A + (size_t)gr * K + k0 + s_off;
                v0 = *(const short8*)ap;
                v1 = *(const short8*)(ap + 8);
            }
            *(short8*)&As[r * STR + s_off]     = v0;
            *(short8*)&As[r * STR + s_off + 8] = v1;
        }
        {
            const unsigned short* sp = Wt + (size_t)b_row * K + k0 + b_chk;
            *(short8*)&Bs[b_row * STR + b_chk] = *(const short8*)sp;
        }
        __syncthreads();

        short8 afr[4], bfr[4];
        #pragma unroll
        for (int rg = 0; rg < 4; ++rg)
            afr[rg] = *(const short8*)&As[(wr + rg * 16 + m16) * STR + q * 8];
        #pragma unroll
        for (int cg = 0; cg < 4; ++cg)
            bfr[cg] = *(const short8*)&Bs[(cg * 16 + m16) * STR + q * 8];
        #pragma unroll
        for (int rg = 0; rg < 4; ++rg)
            #pragma unroll
            for (int cg = 0; cg < 4; ++cg)
                acc[rg][cg] = __builtin_amdgcn_mfma_f32_16x16x32_bf16(
                    afr[rg], bfr[cg], acc[rg][cg], 0, 0, 0);
        __syncthreads();
    }

    float alv[4], arv[4];
    #pragma unroll
    for (int cg = 0; cg < 4; ++cg) {
        alv[cg] = al[cg * 16 + m16];
        arv[cg] = ar[cg * 16 + m16];
    }

    #pragma unroll
    for (int rg = 0; rg < 4; ++rg) {
        #pragma unroll
        for (int r = 0; r < 4; ++r) {
            int gr = row0 + wr + rg * 16 + q * 4 + r;
            float pl = 0.f, pr = 0.f;
            #pragma unroll
            for (int cg = 0; cg < 4; ++cg) {
                pl = fmaf(acc[rg][cg][r], alv[cg], pl);
                pr = fmaf(acc[rg][cg][r], arv[cg], pr);
            }
            #pragma unroll
            for (int off = 1; off < 16; off <<= 1) {
                pl += __shfl_xor(pl, off, 64);
                pr += __shfl_xor(pr, off, 64);
            }
            if (gr < N) {
                ushort4 o;
                o.x = f2b(acc[rg][0][r]); o.y = f2b(acc[rg][1][r]);
                o.z = f2b(acc[rg][2][r]); o.w = f2b(acc[rg][3][r]);
                *(ushort4*)(Cb + (size_t)gr * M + m16 * 4) = o;
                if (m16 == 0) {
                    el[gr] = pl * LOG2E;
                    er[gr] = pr * LOG2E;
                }
            }
        }
    }
}

// ---------------- fused softmax + aggregation (round-7 verified form) ----------
// One P=HH*8-thread group per node; thread t owns STORED dims [8t, 8t+8).
// w = exp2(leaky(el'+er')); normalized by accumulated sum (no max subtraction:
// logits are O(1)). ss-prefetch only (round-3 lesson: full ping-pong pipeline
// costs 40 VGPR -> occupancy cliff; TLP already overlaps). Round-9 lesson:
// degree-sorted perm indirection regresses (block-local access scattering
// costs more than wave-imbalance saving) -- keep consecutive node mapping.
template<int OUTBF, int HH>
__global__ __launch_bounds__(256)
void k_agg_f(const int* __restrict__ row_start, const int* __restrict__ src_sorted,
             const uint4* __restrict__ featp, const float* __restrict__ el,
             const float* __restrict__ er, const float* __restrict__ bias,
             void* __restrict__ outv, int N, int do_relu) {
    constexpr int M = HH * 64;
    constexpr int P = M >> 3;
    constexpr int G = 256 / P;
    const int grp = threadIdx.x / P;
    const int t = threadIdx.x - grp * P;
    const int n = blockIdx.x * G + grp;
    if (n >= N) return;
    const int d0 = t * 8;          // stored-dim base
    const int h = d0 >> 6;
    const float erv = er[n * HH + h];

    const int b0 = row_start[n], b1 = row_start[n + 1];

    float a[8] = {};
    float sum = 0.f;
    int i = b0;

    int ssP[8];
    if (i + 8 <= b1) {
        #pragma unroll
        for (int j = 0; j < 8; ++j) ssP[j] = src_sorted[i + j];
    }
    for (; i + 8 <= b1; i += 8) {
        int ss[8];
        #pragma unroll
        for (int j = 0; j < 8; ++j) ss[j] = ssP[j];
        if (i + 16 <= b1) {
            #pragma unroll
            for (int j = 0; j < 8; ++j) ssP[j] = src_sorted[i + 8 + j];
        }
        float wv[8]; uint4 pv[8];
        #pragma unroll
        for (int j = 0; j < 8; ++j) wv[j] = el[(unsigned)(ss[j] * HH + h)];
        #pragma unroll
        for (int j = 0; j < 8; ++j) pv[j] = featp[(unsigned)(ss[j] * P + t)];
        #pragma unroll
        for (int j = 0; j < 8; ++j) {
            float x = wv[j] + erv;
            x = fmaxf(x, LEAKY * x);
            float w = fexp2(x);
            wv[j] = w;
            sum += w;
        }
        #pragma unroll
        for (int j = 0; j < 8; ++j) {
            a[0] = fmaf(__uint_as_float(pv[j].x << 16),         wv[j], a[0]);
            a[1] = fmaf(__uint_as_float(pv[j].x & 0xFFFF0000u), wv[j], a[1]);
            a[2] = fmaf(__uint_as_float(pv[j].y << 16),         wv[j], a[2]);
            a[3] = fmaf(__uint_as_float(pv[j].y & 0xFFFF0000u), wv[j], a[3]);
            a[4] = fmaf(__uint_as_float(pv[j].z << 16),         wv[j], a[4]);
            a[5] = fmaf(__uint_as_float(pv[j].z & 0xFFFF0000u), wv[j], a[5]);
            a[6] = fmaf(__uint_as_float(pv[j].w << 16),         wv[j], a[6]);
            a[7] = fmaf(__uint_as_float(pv[j].w & 0xFFFF0000u), wv[j], a[7]);
        }
    }
    for (; i + 4 <= b1; i += 4) {
        int ss[4]; float wv[4]; uint4 pv[4];
        #pragma unroll
        for (int j = 0; j < 4; ++j) ss[j] = src_sorted[i + j];
        #pragma unroll
        for (int j = 0; j < 4; ++j) wv[j] = el[(unsigned)(ss[j] * HH + h)];
        #pragma unroll
        for (int j = 0; j < 4; ++j) pv[j] = featp[(unsigned)(ss[j] * P + t)];
        #pragma unroll
        for (int j = 0; j < 4; ++j) {
            float x = wv[j] + erv;
            x = fmaxf(x, LEAKY * x);
            float w = fexp2(x);
            wv[j] = w;
            sum += w;
        }
        #pragma unroll
        for (int j = 0; j < 4; ++j) {
            a[0] = fmaf(__uint_as_float(pv[j].x << 16),         wv[j], a[0]);
            a[1] = fmaf(__uint_as_float(pv[j].x & 0xFFFF0000u), wv[j], a[1]);
            a[2] = fmaf(__uint_as_float(pv[j].y << 16),         wv[j], a[2]);
            a[3] = fmaf(__uint_as_float(pv[j].y & 0xFFFF0000u), wv[j], a[3]);
            a[4] = fmaf(__uint_as_float(pv[j].z << 16),         wv[j], a[4]);
            a[5] = fmaf(__uint_as_float(pv[j].z & 0xFFFF0000u), wv[j], a[5]);
            a[6] = fmaf(__uint_as_float(pv[j].w << 16),         wv[j], a[6]);
            a[7] = fmaf(__uint_as_float(pv[j].w & 0xFFFF0000u), wv[j], a[7]);
        }
    }
    for (; i < b1; ++i) {
        int ss = src_sorted[i];
        float x = el[(unsigned)(ss * HH + h)] + erv;
        uint4 pv = featp[(unsigned)(ss * P + t)];
        x = fmaxf(x, LEAKY * x);
        float w = fexp2(x);
        sum += w;
        a[0] = fmaf(__uint_as_float(pv.x << 16),         w, a[0]);
        a[1] = fmaf(__uint_as_float(pv.x & 0xFFFF0000u), w, a[1]);
        a[2] = fmaf(__uint_as_float(pv.y << 16),         w, a[2]);
        a[3] = fmaf(__uint_as_float(pv.y & 0xFFFF0000u), w, a[3]);
        a[4] = fmaf(__uint_as_float(pv.z << 16),         w, a[4]);
        a[5] = fmaf(__uint_as_float(pv.z & 0xFFFF0000u), w, a[5]);
        a[6] = fmaf(__uint_as_float(pv.w << 16),         w, a[6]);
        a[7] = fmaf(__uint_as_float(pv.w & 0xFFFF0000u), w, a[7]);
    }

    float rs = 1.0f / fmaxf(sum, 1e-30f);
    // bias for stored dim d0+j: true pos = 16*(j&3) + c0 + (j>>2), c0 = (d0&63)>>2
    const int c0 = (d0 & 63) >> 2;
    const float* bh = bias + h * 64 + c0;
    #pragma unroll
    for (int j = 0; j < 8; ++j)
        a[j] = fmaf(a[j], rs, bh[16 * (j & 3) + (j >> 2)]);
    if (do_relu) {
        #pragma unroll
        for (int j = 0; j < 8; ++j) a[j] = fmaxf(a[j], 0.f);
    }
    if (OUTBF) {
        uint4 o;
        o.x = (unsigned)f2b(a[0]) | ((unsigned)f2b(a[1]) << 16);
        o.y = (unsigned)f2b(a[2]) | ((unsigned)f2b(a[3]) << 16);
        o.z = (unsigned)f2b(a[4]) | ((unsigned)f2b(a[5]) << 16);
        o.w = (unsigned)f2b(a[6]) | ((unsigned)f2b(a[7]) << 16);
        *(uint4*)((unsigned short*)outv + (size_t)n * M + d0) = o;
    } else {
        // un-permute: stored d0+j -> true col 16*(j&3)+c0+(j>>2); pairs (j, j+4)
        // are adjacent true cols -> 4 float2 stores at cols 16*j + c0.
        float* op = (float*)outv + (size_t)n * M + h * 64 + c0;
        #pragma unroll
        for (int j = 0; j < 4; ++j)
            *(float2*)(op + 16 * j) = make_float2(a[j], a[j + 4]);
    }
}

// ---------------- host side ----------------

static void run_layer(const unsigned short* A, int K, const unsigned short* Wt,
                      const float* al_, const float* ar_, const float* b_, int H,
                      unsigned short* featb, void* rstOut, bool outBf,
                      float* el, float* er,
                      const int* row_start, const int* src_sorted,
                      int N, int E, bool do_relu, hipStream_t stream) {
    const int M = H * 64;
    if (M % 128 == 0) {
        dim3 gg(M / 128, (N + 127) / 128);
        k_gemm_mfma<<<gg, 256, 0, stream>>>(A, Wt, featb, al_, ar_, el, er, N, K, M);
    } else {
        k_gemm_mfma64<<<(N + 255) / 256, 256, 0, stream>>>(A, Wt, featb, al_, ar_, el, er, N, K);
    }

    int G = 256 / (M / 8);
    int blocks = (N + G - 1) / G;
    if (H == 4) {
        if (outBf)
            k_agg_f<1, 4><<<blocks, 256, 0, stream>>>(row_start, src_sorted,
                                                      (const uint4*)featb, el, er,
                                                      b_, rstOut, N, do_relu ? 1 : 0);
        else
            k_agg_f<0, 4><<<blocks, 256, 0, stream>>>(row_start, src_sorted,
                                                      (const uint4*)featb, el, er,
                                                      b_, rstOut, N, do_relu ? 1 : 0);
    } else {
        if (outBf)
            k_agg_f<1, 1><<<blocks, 256, 0, stream>>>(row_start, src_sorted,
                                                      (const uint4*)featb, el, er,
                                                      b_, rstOut, N, do_relu ? 1 : 0);
        else
            k_agg_f<0, 1><<<blocks, 256, 0, stream>>>(row_start, src_sorted,
                                                      (const uint4*)featb, el, er,
                                                      b_, rstOut, N, do_relu ? 1 : 0);
    }
}

extern "C" void kernel_launch(void* const* d_in, const int* in_sizes, int n_in,
                              void* d_out, int out_size, void* d_ws, size_t ws_size,
                              hipStream_t stream) {
    const float* features = (const float*)d_in[0];
    const int*   src = (const int*)d_in[1];
    const int*   dst = (const int*)d_in[2];
    const float* W1  = (const float*)d_in[3];
    const float* al1 = (const float*)d_in[4];
    const float* ar1 = (const float*)d_in[5];
    const float* b1  = (const float*)d_in[6];
    const float* W2  = (const float*)d_in[7];
    const float* al2 = (const float*)d_in[8];
    const float* ar2 = (const float*)d_in[9];
    const float* b2  = (const float*)d_in[10];
    const float* W3  = (const float*)d_in[11];
    const float* al3 = (const float*)d_in[12];
    const float* ar3 = (const float*)d_in[13];
    const float* b3  = (const float*)d_in[14];

    const int N = in_sizes[0] / 128;   // 50000
    const int E = in_sizes[1];         // 800000
    const int B = (N + 255) >> 8;      // buckets (196)
    const int n4 = N * 128 / 4;        // convert chunks
    const int nbb = (E + NEB - 1) / NEB;   // binning blocks (98)

    float* ws   = (float*)d_ws;
    float* el   = ws;                        // [N,4]
    float* er   = el + (size_t)N * 4;        // [N,4]
    int* row_start  = (int*)(er + (size_t)N * 4);  // [N+1]
    int* src_sorted = row_start + N + 1;            // [E]
    int* ebuf       = src_sorted + E;               // [E]
    int* bbase      = ebuf + E;                     // [257]
    int* hist       = bbase + 257;                  // [nbb*256]
    uintptr_t wp = (uintptr_t)(hist + (size_t)nbb * 256);
    wp = (wp + 15) & ~(uintptr_t)15;
    unsigned short* Wt1   = (unsigned short*)wp;       // [256*128]
    unsigned short* Wt2   = Wt1 + 32768;               // [256*256] K-permuted
    unsigned short* Wt3   = Wt2 + 65536;               // [64*256]  K-permuted
    unsigned short* fconv = Wt3 + 16384;               // [N,128] bf16 features
    unsigned short* featb = fconv + (size_t)N * 128;   // [N,256] GEMM out (stored order)
    unsigned short* rstb  = featb + (size_t)N * 256;   // [N,256] agg out (stored order)

    // ---- fused prep: dst histogram + convert + weight transpose ----
    int prep_total = n4 + 114688;
    int prep_blocks = nbb + (prep_total + 255) / 256;
    k_prep<<<prep_blocks, 256, 0, stream>>>(features, fconv, n4,
                                            W1, W2, W3, Wt1, Wt2, Wt3,
                                            dst, hist, nbb, E, N);

    // ---- bucketed CSR build (deterministic offsets, src packed into ebuf) ----
    k_bin_scatter<<<nbb, 256, 0, stream>>>(dst, src, hist, nbb, bbase,
                                           row_start, ebuf, E, N, B);
    k_csr_build<<<B, 256, 0, stream>>>(ebuf, bbase, row_start, src_sorted, N);

    // layer 1: A=fconv[N,128] -> featb[N,256] (+el/er fused) -> rstb bf16 (+relu)
    run_layer(fconv, 128, Wt1, al1, ar1, b1, 4, featb, rstb, true,
              el, er, row_start, src_sorted, N, E, true, stream);
    // layer 2
    run_layer(rstb, 256, Wt2, al2, ar2, b2, 4, featb, rstb, true,
              el, er, row_start, src_sorted, N, E, true, stream);
    // layer 3: H=1 -> d_out fp32 (mean over 1 head = id), un-permuted write
    run_layer(rstb, 256, Wt3, al3, ar3, b3, 1, featb, d_out, false,
              el, er, row_start, src_sorted, N, E, false, stream);
}